// Round 1
// baseline (395.672 us; speedup 1.0000x reference)
//
#include <hip/hip_runtime.h>

#define T_ 32
#define S_ 4096
#define F_ 256
#define A_ 64

typedef __attribute__((ext_vector_type(8))) short s8v;   // 8 x bf16 (MFMA A/B frag)
typedef __attribute__((ext_vector_type(4))) float f4v;   // 4 x f32  (MFMA C/D frag)
typedef __attribute__((ext_vector_type(4))) short s4v;   // 8-byte packed store

#define MFMA(a, b, c) __builtin_amdgcn_mfma_f32_16x16x32_bf16((a), (b), (c), 0, 0, 0)

__device__ __forceinline__ unsigned short f2bf(float f) {
    unsigned int u = __builtin_bit_cast(unsigned int, f);
    u += 0x7FFFu + ((u >> 16) & 1u);   // round-to-nearest-even
    return (unsigned short)(u >> 16);
}

// ---- pre-pass: convert Wa[64x256], Wb[64x256], Wg[256x256] f32 -> bf16 in d_ws ----
// ws layout (shorts): WaB @0, WbB @16384, WgB @32768   (total 98304 shorts = 192 KB)
__global__ void convert_weights(const float* __restrict__ Wa,
                                const float* __restrict__ Wb,
                                const float* __restrict__ Wg,
                                unsigned short* __restrict__ wsB)
{
    int base = (blockIdx.x * 256 + threadIdx.x) * 4;     // 24576 threads x 4 elems
    const float* src;
    if (base < 16384)      src = Wa + base;
    else if (base < 32768) src = Wb + (base - 16384);
    else                   src = Wg + (base - 32768);
    float4 v = *(const float4*)src;
    s4v p;
    p[0] = (short)f2bf(v.x); p[1] = (short)f2bf(v.y);
    p[2] = (short)f2bf(v.z); p[3] = (short)f2bf(v.w);
    *(s4v*)(wsB + base) = p;
}

// LDS layout (26624 B -> 5-6 blocks/CU; was 43008 -> 3):
//   [0, 16384)      stages A/B: X_s [32][256] bf16, 512 B rows, 16B-chunk swizzle (c+t)&31
//                   stages C/D: featsT [256][32] bf16, 64 B rows, chunk swizzle (c+f)&3
//                   (time-shared: X only needed until afrag regs loaded, featsT written after)
//   [16384, 20480)  theta [32][64] bf16, 128 B rows, chunk swizzle (c+t)&7
//   [20480, 24576)  phi   [32][64] bf16
//   [24576, 26624)  attn  [32][32] bf16, 64 B rows, chunk swizzle (c+t)&3
#define XS_OFF 0
#define FT_OFF 0
#define TH_OFF 16384
#define PH_OFF 20480
#define AT_OFF 24576
#define LDS_BYTES 26624

__global__ __launch_bounds__(256, 5) void fused_temporal(
    const float* __restrict__ X,
    const unsigned short* __restrict__ wsB,
    const float* __restrict__ ba, const float* __restrict__ bb,
    const float* __restrict__ bg,
    float* __restrict__ out)
{
    __shared__ alignas(16) unsigned char smem[LDS_BYTES];
    const int tid  = threadIdx.x;
    const int wave = tid >> 6;
    const int lane = tid & 63;
    const int quad = lane >> 4;
    const int l15  = lane & 15;
    const int s    = blockIdx.x;

    const unsigned short* WaB = wsB;
    const unsigned short* WbB = wsB + 16384;
    const unsigned short* WgB = wsB + 32768;

    // ---- Stage A: stage X_s [32 rows x 256 f32], convert to bf16, XOR-swizzled 16B chunks ----
    #pragma unroll
    for (int i = 0; i < 4; ++i) {
        int linear = i * 256 + tid;            // 0..1023 bf16 chunks of 16 B (8 elems)
        int t = linear >> 5;                   // row 0..31
        int c = linear & 31;                   // 8-elem chunk in row
        const float* xp = X + ((size_t)(t * S_ + s)) * F_ + c * 8;
        float4 v0 = *(const float4*)(xp);
        float4 v1 = *(const float4*)(xp + 4);
        s8v p;
        p[0] = (short)f2bf(v0.x); p[1] = (short)f2bf(v0.y);
        p[2] = (short)f2bf(v0.z); p[3] = (short)f2bf(v0.w);
        p[4] = (short)f2bf(v1.x); p[5] = (short)f2bf(v1.y);
        p[6] = (short)f2bf(v1.z); p[7] = (short)f2bf(v1.w);
        *(s8v*)(&smem[XS_OFF + t * 512 + (((c + t) & 31) << 4)]) = p;
    }
    __syncthreads();

    // ---- Stage B: A-fragments of X_s into regs, then theta & phi ----
    // A[m=lane&15][k=quad*8+j], 2 m-tiles x 8 k-steps (64 VGPRs, live to end of stage C)
    s8v afrag[2][8];
    #pragma unroll
    for (int mt = 0; mt < 2; ++mt) {
        int t = l15 + 16 * mt;
        #pragma unroll
        for (int ks = 0; ks < 8; ++ks) {
            int chunk = 4 * ks + quad;
            afrag[mt][ks] = *(const s8v*)(&smem[XS_OFF + t * 512 + (((chunk + t) & 31) << 4)]);
        }
    }

    // theta & phi, wave w owns cols [16w,16w+16)
    {
        int n0 = 16 * wave;
        f4v ta0 = {0.f,0.f,0.f,0.f}, ta1 = {0.f,0.f,0.f,0.f};
        f4v pa0 = {0.f,0.f,0.f,0.f}, pa1 = {0.f,0.f,0.f,0.f};
        const unsigned short* wa_row = WaB + (size_t)(n0 + l15) * F_ + quad * 8;
        const unsigned short* wb_row = WbB + (size_t)(n0 + l15) * F_ + quad * 8;
        #pragma unroll
        for (int ks = 0; ks < 8; ++ks) {
            s8v bfa = *(const s8v*)(wa_row + ks * 32);
            s8v bfb = *(const s8v*)(wb_row + ks * 32);
            ta0 = MFMA(afrag[0][ks], bfa, ta0);
            ta1 = MFMA(afrag[1][ks], bfa, ta1);
            pa0 = MFMA(afrag[0][ks], bfb, pa0);
            pa1 = MFMA(afrag[1][ks], bfb, pa1);
        }
        float biasa = ba[n0 + l15];
        float biasb = bb[n0 + l15];
        int a_col = n0 + l15;
        int chunk = a_col >> 3;
        int sub   = (a_col & 7) * 2;
        #pragma unroll
        for (int mt = 0; mt < 2; ++mt) {
            f4v va = mt ? ta1 : ta0;
            f4v vb = mt ? pa1 : pa0;
            #pragma unroll
            for (int r = 0; r < 4; ++r) {
                int t  = quad * 4 + r + 16 * mt;
                int sw = ((chunk + t) & 7) << 4;
                *(unsigned short*)(&smem[TH_OFF + t * 128 + sw + sub]) = f2bf(va[r] + biasa);
                *(unsigned short*)(&smem[PH_OFF + t * 128 + sw + sub]) = f2bf(vb[r] + biasb);
            }
        }
    }
    __syncthreads();
    // Barrier guarantees: all waves' afrag LDS reads done (X region now reusable as featsT),
    // and theta/phi fully written.

    // ---- Stage C: attn (reads TH/PH, writes AT) + feats (writes featsT over X region) ----
    {
        // attn[t][u] = sum_a theta[t][a] * phi[u][a]; wave w -> tile (w>>1, w&1)
        int mt2 = wave >> 1, nt2 = wave & 1;
        int t2 = l15 + 16 * mt2;
        int u2 = l15 + 16 * nt2;
        f4v acc2 = {0.f,0.f,0.f,0.f};
        #pragma unroll
        for (int ks = 0; ks < 2; ++ks) {
            int chunk = 4 * ks + quad;
            s8v av = *(const s8v*)(&smem[TH_OFF + t2 * 128 + (((chunk + t2) & 7) << 4)]);
            s8v bv = *(const s8v*)(&smem[PH_OFF + u2 * 128 + (((chunk + u2) & 7) << 4)]);
            acc2 = MFMA(av, bv, acc2);
        }
        {
            int chunk = u2 >> 3;
            int sub   = (u2 & 7) * 2;
            #pragma unroll
            for (int r = 0; r < 4; ++r) {
                int tt = quad * 4 + r + 16 * mt2;
                *(unsigned short*)(&smem[AT_OFF + tt * 64 + (((chunk + tt) & 3) << 4) + sub]) = f2bf(acc2[r]);
            }
        }

        // feats, wave w owns cols [64w,64w+64); stored transposed [f][u] over old X region
        #pragma unroll
        for (int g = 0; g < 4; ++g) {
            int n0 = 64 * wave + 16 * g;
            f4v fa0 = {0.f,0.f,0.f,0.f}, fa1 = {0.f,0.f,0.f,0.f};
            const unsigned short* wg_row = WgB + (size_t)(n0 + l15) * F_ + quad * 8;
            #pragma unroll
            for (int ks = 0; ks < 8; ++ks) {
                s8v bf = *(const s8v*)(wg_row + ks * 32);
                fa0 = MFMA(afrag[0][ks], bf, fa0);
                fa1 = MFMA(afrag[1][ks], bf, fa1);
            }
            float biasg = bg[n0 + l15];
            int f = n0 + l15;
            #pragma unroll
            for (int mt = 0; mt < 2; ++mt) {
                f4v v = mt ? fa1 : fa0;
                int u0 = quad * 4 + 16 * mt;            // 4 consecutive u per lane
                s4v pk;
                #pragma unroll
                for (int r = 0; r < 4; ++r) pk[r] = (short)f2bf(v[r] + biasg);
                int addr = FT_OFF + f * 64 + ((((u0 >> 3) + f) & 3) << 4) + (u0 & 7) * 2;
                *(s4v*)(&smem[addr]) = pk;              // ds_write_b64
            }
        }
    }
    __syncthreads();

    // ---- Stage D: out^T[f][t] = sum_u featsT[f][u] * attn[t][u]  (operand-swapped) ----
    // D: col=lane&15 -> t, row=quad*4+r -> f  => lane holds 4 CONSECUTIVE f for one t
    // => 8 dwordx4 stores/thread instead of 32 scalar dword stores.
    {
        s8v battn[2];
        #pragma unroll
        for (int nt = 0; nt < 2; ++nt) {
            int t = l15 + 16 * nt;
            battn[nt] = *(const s8v*)(&smem[AT_OFF + t * 64 + (((quad + t) & 3) << 4)]);
        }
        #pragma unroll
        for (int g = 0; g < 4; ++g) {
            int fm = 64 * wave + 16 * g + l15;          // A-frag row (f index)
            s8v av = *(const s8v*)(&smem[FT_OFF + fm * 64 + (((quad + fm) & 3) << 4)]);
            int f0 = 64 * wave + 16 * g + 4 * quad;     // this lane's 4 output f
            #pragma unroll
            for (int nt = 0; nt < 2; ++nt) {
                f4v z = {0.f,0.f,0.f,0.f};
                f4v acc = MFMA(av, battn[nt], z);
                int t = l15 + 16 * nt;
                float4 st;
                st.x = acc[0]; st.y = acc[1]; st.z = acc[2]; st.w = acc[3];
                *(float4*)(out + ((size_t)(t * S_ + s)) * F_ + f0) = st;
            }
        }
    }
}

extern "C" void kernel_launch(void* const* d_in, const int* in_sizes, int n_in,
                              void* d_out, int out_size, void* d_ws, size_t ws_size,
                              hipStream_t stream) {
    (void)in_sizes; (void)n_in; (void)ws_size; (void)out_size;
    const float* X  = (const float*)d_in[0];   // batch_data [T*S, F] f32
    // d_in[1] = xywh (dead path)
    const float* Wa = (const float*)d_in[2];
    const float* ba = (const float*)d_in[3];
    const float* Wb = (const float*)d_in[4];
    const float* bb = (const float*)d_in[5];
    const float* Wg = (const float*)d_in[6];
    const float* bg = (const float*)d_in[7];
    // d_in[8] = Wh, d_in[9] = bh (dead path)
    float* out = (float*)d_out;
    unsigned short* wsB = (unsigned short*)d_ws;   // 192 KB bf16 weights

    convert_weights<<<dim3(96), dim3(256), 0, stream>>>(Wa, Wb, Wg, wsB);
    fused_temporal<<<dim3(S_), dim3(256), 0, stream>>>(X, wsB, ba, bb, bg, out);
}

// Round 2
// 323.582 us; speedup vs baseline: 1.2228x; 1.2228x over previous
//
#include <hip/hip_runtime.h>

#define T_ 32
#define S_ 4096
#define F_ 256
#define A_ 64

typedef __attribute__((ext_vector_type(8))) short s8v;   // 8 x bf16 (MFMA A/B frag)
typedef __attribute__((ext_vector_type(4))) float f4v;   // 4 x f32  (MFMA C/D frag)
typedef __attribute__((ext_vector_type(4))) short s4v;   // 8-byte packed store

#define MFMA(a, b, c) __builtin_amdgcn_mfma_f32_16x16x32_bf16((a), (b), (c), 0, 0, 0)

__device__ __forceinline__ unsigned short f2bf(float f) {
    unsigned int u = __builtin_bit_cast(unsigned int, f);
    u += 0x7FFFu + ((u >> 16) & 1u);   // round-to-nearest-even
    return (unsigned short)(u >> 16);
}

// ---- pre-pass: convert Wa[64x256], Wb[64x256], Wg[256x256] f32 -> bf16 in d_ws ----
// ws layout (shorts): WaB @0, WbB @16384, WgB @32768   (total 98304 shorts = 192 KB)
__global__ void convert_weights(const float* __restrict__ Wa,
                                const float* __restrict__ Wb,
                                const float* __restrict__ Wg,
                                unsigned short* __restrict__ wsB)
{
    int base = (blockIdx.x * 256 + threadIdx.x) * 4;     // 24576 threads x 4 elems
    const float* src;
    if (base < 16384)      src = Wa + base;
    else if (base < 32768) src = Wb + (base - 16384);
    else                   src = Wg + (base - 32768);
    float4 v = *(const float4*)src;
    s4v p;
    p[0] = (short)f2bf(v.x); p[1] = (short)f2bf(v.y);
    p[2] = (short)f2bf(v.z); p[3] = (short)f2bf(v.w);
    *(s4v*)(wsB + base) = p;
}

// LDS layout (26624 B):
//   [0, 16384)      stages A/B: X_s [32][256] bf16, 512 B rows, 16B-chunk swizzle (c+t)&31
//                   stages C/D: featsT [256][32] bf16, 64 B rows, chunk swizzle (c+f)&3
//                   (time-shared: X only needed until afrag regs loaded, featsT written after)
//   [16384, 20480)  theta [32][64] bf16, 128 B rows, chunk swizzle (c+t)&7
//   [20480, 24576)  phi   [32][64] bf16
//   [24576, 26624)  attn  [32][32] bf16, 64 B rows, chunk swizzle (c+t)&3
#define XS_OFF 0
#define FT_OFF 0
#define TH_OFF 16384
#define PH_OFF 20480
#define AT_OFF 24576
#define LDS_BYTES 26624

// launch_bounds(256, 4): VGPR cap 128 — fits afrag[2][8] (64) + accs without spill.
// (256,5) capped at ~102 VGPRs and spilled afrag to scratch: VGPR_Count=48,
// +380 MB HBM traffic, dur 145->226 us. Do NOT raise the second arg past 4.
__global__ __launch_bounds__(256, 4) void fused_temporal(
    const float* __restrict__ X,
    const unsigned short* __restrict__ wsB,
    const float* __restrict__ ba, const float* __restrict__ bb,
    const float* __restrict__ bg,
    float* __restrict__ out)
{
    __shared__ alignas(16) unsigned char smem[LDS_BYTES];
    const int tid  = threadIdx.x;
    const int wave = tid >> 6;
    const int lane = tid & 63;
    const int quad = lane >> 4;
    const int l15  = lane & 15;
    const int s    = blockIdx.x;

    const unsigned short* WaB = wsB;
    const unsigned short* WbB = wsB + 16384;
    const unsigned short* WgB = wsB + 32768;

    // ---- Stage A: stage X_s [32 rows x 256 f32], convert to bf16, XOR-swizzled 16B chunks ----
    #pragma unroll
    for (int i = 0; i < 4; ++i) {
        int linear = i * 256 + tid;            // 0..1023 bf16 chunks of 16 B (8 elems)
        int t = linear >> 5;                   // row 0..31
        int c = linear & 31;                   // 8-elem chunk in row
        const float* xp = X + ((size_t)(t * S_ + s)) * F_ + c * 8;
        float4 v0 = *(const float4*)(xp);
        float4 v1 = *(const float4*)(xp + 4);
        s8v p;
        p[0] = (short)f2bf(v0.x); p[1] = (short)f2bf(v0.y);
        p[2] = (short)f2bf(v0.z); p[3] = (short)f2bf(v0.w);
        p[4] = (short)f2bf(v1.x); p[5] = (short)f2bf(v1.y);
        p[6] = (short)f2bf(v1.z); p[7] = (short)f2bf(v1.w);
        *(s8v*)(&smem[XS_OFF + t * 512 + (((c + t) & 31) << 4)]) = p;
    }
    __syncthreads();

    // ---- Stage B: A-fragments of X_s into regs, then theta & phi ----
    // A[m=lane&15][k=quad*8+j], 2 m-tiles x 8 k-steps (64 VGPRs, live to end of stage C)
    s8v afrag[2][8];
    #pragma unroll
    for (int mt = 0; mt < 2; ++mt) {
        int t = l15 + 16 * mt;
        #pragma unroll
        for (int ks = 0; ks < 8; ++ks) {
            int chunk = 4 * ks + quad;
            afrag[mt][ks] = *(const s8v*)(&smem[XS_OFF + t * 512 + (((chunk + t) & 31) << 4)]);
        }
    }

    // theta & phi, wave w owns cols [16w,16w+16)
    {
        int n0 = 16 * wave;
        f4v ta0 = {0.f,0.f,0.f,0.f}, ta1 = {0.f,0.f,0.f,0.f};
        f4v pa0 = {0.f,0.f,0.f,0.f}, pa1 = {0.f,0.f,0.f,0.f};
        const unsigned short* wa_row = WaB + (size_t)(n0 + l15) * F_ + quad * 8;
        const unsigned short* wb_row = WbB + (size_t)(n0 + l15) * F_ + quad * 8;
        #pragma unroll
        for (int ks = 0; ks < 8; ++ks) {
            s8v bfa = *(const s8v*)(wa_row + ks * 32);
            s8v bfb = *(const s8v*)(wb_row + ks * 32);
            ta0 = MFMA(afrag[0][ks], bfa, ta0);
            ta1 = MFMA(afrag[1][ks], bfa, ta1);
            pa0 = MFMA(afrag[0][ks], bfb, pa0);
            pa1 = MFMA(afrag[1][ks], bfb, pa1);
        }
        float biasa = ba[n0 + l15];
        float biasb = bb[n0 + l15];
        int a_col = n0 + l15;
        int chunk = a_col >> 3;
        int sub   = (a_col & 7) * 2;
        #pragma unroll
        for (int mt = 0; mt < 2; ++mt) {
            f4v va = mt ? ta1 : ta0;
            f4v vb = mt ? pa1 : pa0;
            #pragma unroll
            for (int r = 0; r < 4; ++r) {
                int t  = quad * 4 + r + 16 * mt;
                int sw = ((chunk + t) & 7) << 4;
                *(unsigned short*)(&smem[TH_OFF + t * 128 + sw + sub]) = f2bf(va[r] + biasa);
                *(unsigned short*)(&smem[PH_OFF + t * 128 + sw + sub]) = f2bf(vb[r] + biasb);
            }
        }
    }
    __syncthreads();
    // Barrier guarantees: all waves' afrag LDS reads done (X region now reusable as featsT),
    // and theta/phi fully written.

    // ---- Stage C: attn (reads TH/PH, writes AT) + feats (writes featsT over X region) ----
    {
        // attn[t][u] = sum_a theta[t][a] * phi[u][a]; wave w -> tile (w>>1, w&1)
        int mt2 = wave >> 1, nt2 = wave & 1;
        int t2 = l15 + 16 * mt2;
        int u2 = l15 + 16 * nt2;
        f4v acc2 = {0.f,0.f,0.f,0.f};
        #pragma unroll
        for (int ks = 0; ks < 2; ++ks) {
            int chunk = 4 * ks + quad;
            s8v av = *(const s8v*)(&smem[TH_OFF + t2 * 128 + (((chunk + t2) & 7) << 4)]);
            s8v bv = *(const s8v*)(&smem[PH_OFF + u2 * 128 + (((chunk + u2) & 7) << 4)]);
            acc2 = MFMA(av, bv, acc2);
        }
        {
            int chunk = u2 >> 3;
            int sub   = (u2 & 7) * 2;
            #pragma unroll
            for (int r = 0; r < 4; ++r) {
                int tt = quad * 4 + r + 16 * mt2;
                *(unsigned short*)(&smem[AT_OFF + tt * 64 + (((chunk + tt) & 3) << 4) + sub]) = f2bf(acc2[r]);
            }
        }

        // feats, wave w owns cols [64w,64w+64); stored transposed [f][u] over old X region
        #pragma unroll
        for (int g = 0; g < 4; ++g) {
            int n0 = 64 * wave + 16 * g;
            f4v fa0 = {0.f,0.f,0.f,0.f}, fa1 = {0.f,0.f,0.f,0.f};
            const unsigned short* wg_row = WgB + (size_t)(n0 + l15) * F_ + quad * 8;
            #pragma unroll
            for (int ks = 0; ks < 8; ++ks) {
                s8v bf = *(const s8v*)(wg_row + ks * 32);
                fa0 = MFMA(afrag[0][ks], bf, fa0);
                fa1 = MFMA(afrag[1][ks], bf, fa1);
            }
            float biasg = bg[n0 + l15];
            int f = n0 + l15;
            #pragma unroll
            for (int mt = 0; mt < 2; ++mt) {
                f4v v = mt ? fa1 : fa0;
                int u0 = quad * 4 + 16 * mt;            // 4 consecutive u per lane
                s4v pk;
                #pragma unroll
                for (int r = 0; r < 4; ++r) pk[r] = (short)f2bf(v[r] + biasg);
                int addr = FT_OFF + f * 64 + ((((u0 >> 3) + f) & 3) << 4) + (u0 & 7) * 2;
                *(s4v*)(&smem[addr]) = pk;              // ds_write_b64
            }
        }
    }
    __syncthreads();

    // ---- Stage D: out^T[f][t] = sum_u featsT[f][u] * attn[t][u]  (operand-swapped) ----
    // D: col=lane&15 -> t, row=quad*4+r -> f  => lane holds 4 CONSECUTIVE f for one t
    // => 8 dwordx4 stores/thread instead of 32 scalar dword stores.
    {
        s8v battn[2];
        #pragma unroll
        for (int nt = 0; nt < 2; ++nt) {
            int t = l15 + 16 * nt;
            battn[nt] = *(const s8v*)(&smem[AT_OFF + t * 64 + (((quad + t) & 3) << 4)]);
        }
        #pragma unroll
        for (int g = 0; g < 4; ++g) {
            int fm = 64 * wave + 16 * g + l15;          // A-frag row (f index)
            s8v av = *(const s8v*)(&smem[FT_OFF + fm * 64 + (((quad + fm) & 3) << 4)]);
            int f0 = 64 * wave + 16 * g + 4 * quad;     // this lane's 4 output f
            #pragma unroll
            for (int nt = 0; nt < 2; ++nt) {
                f4v z = {0.f,0.f,0.f,0.f};
                f4v acc = MFMA(av, battn[nt], z);
                int t = l15 + 16 * nt;
                float4 st;
                st.x = acc[0]; st.y = acc[1]; st.z = acc[2]; st.w = acc[3];
                *(float4*)(out + ((size_t)(t * S_ + s)) * F_ + f0) = st;
            }
        }
    }
}

extern "C" void kernel_launch(void* const* d_in, const int* in_sizes, int n_in,
                              void* d_out, int out_size, void* d_ws, size_t ws_size,
                              hipStream_t stream) {
    (void)in_sizes; (void)n_in; (void)ws_size; (void)out_size;
    const float* X  = (const float*)d_in[0];   // batch_data [T*S, F] f32
    // d_in[1] = xywh (dead path)
    const float* Wa = (const float*)d_in[2];
    const float* ba = (const float*)d_in[3];
    const float* Wb = (const float*)d_in[4];
    const float* bb = (const float*)d_in[5];
    const float* Wg = (const float*)d_in[6];
    const float* bg = (const float*)d_in[7];
    // d_in[8] = Wh, d_in[9] = bh (dead path)
    float* out = (float*)d_out;
    unsigned short* wsB = (unsigned short*)d_ws;   // 192 KB bf16 weights

    convert_weights<<<dim3(96), dim3(256), 0, stream>>>(Wa, Wb, Wg, wsB);
    fused_temporal<<<dim3(S_), dim3(256), 0, stream>>>(X, wsB, ba, bb, bg, out);
}

// Round 3
// 322.210 us; speedup vs baseline: 1.2280x; 1.0043x over previous
//
#include <hip/hip_runtime.h>

#define T_ 32
#define S_ 4096
#define F_ 256
#define A_ 64

typedef __attribute__((ext_vector_type(8))) short s8v;   // 8 x bf16 (MFMA A/B frag)
typedef __attribute__((ext_vector_type(4))) float f4v;   // 4 x f32  (MFMA C/D frag)
typedef __attribute__((ext_vector_type(4))) short s4v;   // 8-byte packed store

#define MFMA(a, b, c) __builtin_amdgcn_mfma_f32_16x16x32_bf16((a), (b), (c), 0, 0, 0)

__device__ __forceinline__ unsigned short f2bf(float f) {
    unsigned int u = __builtin_bit_cast(unsigned int, f);
    u += 0x7FFFu + ((u >> 16) & 1u);   // round-to-nearest-even
    return (unsigned short)(u >> 16);
}

// ---- pre-pass: convert Wa[64x256], Wb[64x256], Wg[256x256] f32 -> bf16 in d_ws ----
__global__ void convert_weights(const float* __restrict__ Wa,
                                const float* __restrict__ Wb,
                                const float* __restrict__ Wg,
                                unsigned short* __restrict__ wsB)
{
    int base = (blockIdx.x * 256 + threadIdx.x) * 4;     // 24576 threads x 4 elems
    const float* src;
    if (base < 16384)      src = Wa + base;
    else if (base < 32768) src = Wb + (base - 16384);
    else                   src = Wg + (base - 32768);
    float4 v = *(const float4*)src;
    s4v p;
    p[0] = (short)f2bf(v.x); p[1] = (short)f2bf(v.y);
    p[2] = (short)f2bf(v.z); p[3] = (short)f2bf(v.w);
    *(s4v*)(wsB + base) = p;
}

// LDS layout (43008 B, 3 blocks/CU):
//   [0, 16384)      X_s [32][256] bf16, 512 B rows, 16B-chunk swizzle (c+t)&31  (live whole kernel)
//   [16384, 20480)  theta [32][64] bf16, 128 B rows, chunk swizzle (c+t)&7
//   [20480, 24576)  phi   [32][64] bf16
//   [24576, 26624)  attn  [32][32] bf16, 64 B rows, chunk swizzle (c+t)&3
//   [26624, 43008)  featsT[256][32] bf16, 64 B rows, chunk swizzle (c+f)&3 (wave-private rows)
#define XS_OFF 0
#define TH_OFF 16384
#define PH_OFF 20480
#define AT_OFF 24576
#define FT_OFF 26624
#define LDS_BYTES 43008

// VGPR budget notes: weights are explicitly register-prefetched (wa/wb: 64 VGPR in
// stage A/B, wg double-buffer: 64 VGPR in stage C). A-fragments are STREAMED from
// X-LDS per k-step (not held: that would push peak >144 and spill at the 128 cap).
// (256,5) previously spilled catastrophically (+380 MB scratch traffic). Keep (256,4).
__global__ __launch_bounds__(256, 4) void fused_temporal(
    const float* __restrict__ X,
    const unsigned short* __restrict__ wsB,
    const float* __restrict__ ba, const float* __restrict__ bb,
    const float* __restrict__ bg,
    float* __restrict__ out)
{
    __shared__ alignas(16) unsigned char smem[LDS_BYTES];
    const int tid  = threadIdx.x;
    const int wave = tid >> 6;
    const int lane = tid & 63;
    const int quad = lane >> 4;
    const int l15  = lane & 15;
    const int s    = blockIdx.x;

    const unsigned short* WaB = wsB;
    const unsigned short* WbB = wsB + 16384;
    const unsigned short* WgB = wsB + 32768;

    // ---- Stage A: issue X loads (HBM), then wa/wb prefetch (L2) — all in flight together ----
    float4 xv[8];
    #pragma unroll
    for (int i = 0; i < 4; ++i) {
        int linear = i * 256 + tid;            // 0..1023 chunks of 8 f32
        int t = linear >> 5;
        int c = linear & 31;
        const float* xp = X + ((size_t)(t * S_ + s)) * F_ + c * 8;
        xv[2 * i]     = *(const float4*)(xp);
        xv[2 * i + 1] = *(const float4*)(xp + 4);
    }

    // theta/phi weight fragments: wave w owns cols [16w,16w+16)
    s8v wafrag[8], wbfrag[8];
    {
        const unsigned short* wa_row = WaB + (size_t)(16 * wave + l15) * F_ + quad * 8;
        const unsigned short* wb_row = WbB + (size_t)(16 * wave + l15) * F_ + quad * 8;
        #pragma unroll
        for (int ks = 0; ks < 8; ++ks) {
            wafrag[ks] = *(const s8v*)(wa_row + ks * 32);
            wbfrag[ks] = *(const s8v*)(wb_row + ks * 32);
        }
    }

    // convert X to bf16 and stage to LDS (swizzled 16B chunks)
    #pragma unroll
    for (int i = 0; i < 4; ++i) {
        int linear = i * 256 + tid;
        int t = linear >> 5;
        int c = linear & 31;
        float4 v0 = xv[2 * i];
        float4 v1 = xv[2 * i + 1];
        s8v p;
        p[0] = (short)f2bf(v0.x); p[1] = (short)f2bf(v0.y);
        p[2] = (short)f2bf(v0.z); p[3] = (short)f2bf(v0.w);
        p[4] = (short)f2bf(v1.x); p[5] = (short)f2bf(v1.y);
        p[6] = (short)f2bf(v1.z); p[7] = (short)f2bf(v1.w);
        *(s8v*)(&smem[XS_OFF + t * 512 + (((c + t) & 31) << 4)]) = p;
    }
    __syncthreads();

    // ---- Stage B: theta & phi (A streamed from LDS, weights from regs) ----
    s8v wg[2][8];   // wg double-buffer, loaded after wa/wb die
    {
        f4v ta0 = {0.f,0.f,0.f,0.f}, ta1 = {0.f,0.f,0.f,0.f};
        f4v pa0 = {0.f,0.f,0.f,0.f}, pa1 = {0.f,0.f,0.f,0.f};
        #pragma unroll
        for (int ks = 0; ks < 8; ++ks) {
            int chunk = 4 * ks + quad;
            s8v a0 = *(const s8v*)(&smem[XS_OFF + l15 * 512 + (((chunk + l15) & 31) << 4)]);
            s8v a1 = *(const s8v*)(&smem[XS_OFF + (l15 + 16) * 512 + (((chunk + l15 + 16) & 31) << 4)]);
            ta0 = MFMA(a0, wafrag[ks], ta0);
            ta1 = MFMA(a1, wafrag[ks], ta1);
            pa0 = MFMA(a0, wbfrag[ks], pa0);
            pa1 = MFMA(a1, wbfrag[ks], pa1);
        }

        // prefetch Wg fragments for g=0,1 (reuses wa/wb register space; lands during epilogue+attn)
        #pragma unroll
        for (int g = 0; g < 2; ++g) {
            const unsigned short* wg_row = WgB + (size_t)(64 * wave + 16 * g + l15) * F_ + quad * 8;
            #pragma unroll
            for (int ks = 0; ks < 8; ++ks) wg[g][ks] = *(const s8v*)(wg_row + ks * 32);
        }

        float biasa = ba[16 * wave + l15];
        float biasb = bb[16 * wave + l15];
        int a_col = 16 * wave + l15;
        int chunk = a_col >> 3;
        int sub   = (a_col & 7) * 2;
        #pragma unroll
        for (int mt = 0; mt < 2; ++mt) {
            f4v va = mt ? ta1 : ta0;
            f4v vb = mt ? pa1 : pa0;
            #pragma unroll
            for (int r = 0; r < 4; ++r) {
                int t  = quad * 4 + r + 16 * mt;
                int sw = ((chunk + t) & 7) << 4;
                *(unsigned short*)(&smem[TH_OFF + t * 128 + sw + sub]) = f2bf(va[r] + biasa);
                *(unsigned short*)(&smem[PH_OFF + t * 128 + sw + sub]) = f2bf(vb[r] + biasb);
            }
        }
    }
    __syncthreads();

    // ---- Attn phase: attn[t][u] = sum_a theta[t][a]*phi[u][a]; wave w -> tile (w>>1, w&1) ----
    {
        int mt2 = wave >> 1, nt2 = wave & 1;
        int t2 = l15 + 16 * mt2;
        int u2 = l15 + 16 * nt2;
        f4v acc2 = {0.f,0.f,0.f,0.f};
        #pragma unroll
        for (int ks = 0; ks < 2; ++ks) {
            int chunk = 4 * ks + quad;
            s8v av = *(const s8v*)(&smem[TH_OFF + t2 * 128 + (((chunk + t2) & 7) << 4)]);
            s8v bv = *(const s8v*)(&smem[PH_OFF + u2 * 128 + (((chunk + u2) & 7) << 4)]);
            acc2 = MFMA(av, bv, acc2);
        }
        int chunk = u2 >> 3;
        int sub   = (u2 & 7) * 2;
        #pragma unroll
        for (int r = 0; r < 4; ++r) {
            int tt = quad * 4 + r + 16 * mt2;
            *(unsigned short*)(&smem[AT_OFF + tt * 64 + (((chunk + tt) & 3) << 4) + sub]) = f2bf(acc2[r]);
        }
    }
    __syncthreads();
    // No further barriers: featsT rows are wave-private (wave w writes+reads f in [64w,64w+64)).

    // ---- Stage C/D fused, per 16-col group g: feats -> featsT (LDS round-trip) -> PV -> store ----
    {
        s8v battn[2];
        #pragma unroll
        for (int nt = 0; nt < 2; ++nt) {
            int t = l15 + 16 * nt;
            battn[nt] = *(const s8v*)(&smem[AT_OFF + t * 64 + (((quad + t) & 3) << 4)]);
        }

        #pragma unroll
        for (int g = 0; g < 4; ++g) {
            int n0 = 64 * wave + 16 * g;
            f4v fa0 = {0.f,0.f,0.f,0.f}, fa1 = {0.f,0.f,0.f,0.f};
            #pragma unroll
            for (int ks = 0; ks < 8; ++ks) {
                int chunk = 4 * ks + quad;
                s8v a0 = *(const s8v*)(&smem[XS_OFF + l15 * 512 + (((chunk + l15) & 31) << 4)]);
                s8v a1 = *(const s8v*)(&smem[XS_OFF + (l15 + 16) * 512 + (((chunk + l15 + 16) & 31) << 4)]);
                fa0 = MFMA(a0, wg[g & 1][ks], fa0);
                fa1 = MFMA(a1, wg[g & 1][ks], fa1);
            }
            // prefetch wg for g+2 into the buffer just freed
            if (g < 2) {
                const unsigned short* wg_row = WgB + (size_t)(64 * wave + 16 * (g + 2) + l15) * F_ + quad * 8;
                #pragma unroll
                for (int ks = 0; ks < 8; ++ks) wg[g & 1][ks] = *(const s8v*)(wg_row + ks * 32);
            }

            float biasg = bg[n0 + l15];
            int f = n0 + l15;
            #pragma unroll
            for (int mt = 0; mt < 2; ++mt) {
                f4v v = mt ? fa1 : fa0;
                int u0 = quad * 4 + 16 * mt;            // 4 consecutive u per lane
                s4v pk;
                #pragma unroll
                for (int r = 0; r < 4; ++r) pk[r] = (short)f2bf(v[r] + biasg);
                int addr = FT_OFF + f * 64 + ((((u0 >> 3) + f) & 3) << 4) + (u0 & 7) * 2;
                *(s4v*)(&smem[addr]) = pk;              // ds_write_b64 (wave-private row)
            }

            // read back as PV A-operand: featsT row f, u-chunk = quad (compiler orders via lgkmcnt)
            s8v av = *(const s8v*)(&smem[FT_OFF + f * 64 + (((quad + f) & 3) << 4)]);
            int f0 = n0 + 4 * quad;                     // this lane's 4 output f
            #pragma unroll
            for (int nt = 0; nt < 2; ++nt) {
                f4v z = {0.f,0.f,0.f,0.f};
                f4v acc = MFMA(av, battn[nt], z);
                int t = l15 + 16 * nt;
                float4 st;
                st.x = acc[0]; st.y = acc[1]; st.z = acc[2]; st.w = acc[3];
                *(float4*)(out + ((size_t)(t * S_ + s)) * F_ + f0) = st;
            }
        }
    }
}

extern "C" void kernel_launch(void* const* d_in, const int* in_sizes, int n_in,
                              void* d_out, int out_size, void* d_ws, size_t ws_size,
                              hipStream_t stream) {
    (void)in_sizes; (void)n_in; (void)ws_size; (void)out_size;
    const float* X  = (const float*)d_in[0];   // batch_data [T*S, F] f32
    // d_in[1] = xywh (dead path)
    const float* Wa = (const float*)d_in[2];
    const float* ba = (const float*)d_in[3];
    const float* Wb = (const float*)d_in[4];
    const float* bb = (const float*)d_in[5];
    const float* Wg = (const float*)d_in[6];
    const float* bg = (const float*)d_in[7];
    // d_in[8] = Wh, d_in[9] = bh (dead path)
    float* out = (float*)d_out;
    unsigned short* wsB = (unsigned short*)d_ws;   // 192 KB bf16 weights

    convert_weights<<<dim3(96), dim3(256), 0, stream>>>(Wa, Wb, Wg, wsB);
    fused_temporal<<<dim3(S_), dim3(256), 0, stream>>>(X, wsB, ba, bb, bg, out);
}

// Round 4
// 314.617 us; speedup vs baseline: 1.2576x; 1.0241x over previous
//
#include <hip/hip_runtime.h>

#define T_ 32
#define S_ 4096
#define F_ 256
#define A_ 64
#define NS 2   // s-values per block: amortizes weight loads 2x, doubles MFMA per phase

typedef __attribute__((ext_vector_type(8))) short s8v;   // 8 x bf16 (MFMA A/B frag)
typedef __attribute__((ext_vector_type(4))) float f4v;   // 4 x f32  (MFMA C/D frag)
typedef __attribute__((ext_vector_type(4))) short s4v;   // 8-byte packed store

#define MFMA(a, b, c) __builtin_amdgcn_mfma_f32_16x16x32_bf16((a), (b), (c), 0, 0, 0)

__device__ __forceinline__ unsigned short f2bf(float f) {
    unsigned int u = __builtin_bit_cast(unsigned int, f);
    u += 0x7FFFu + ((u >> 16) & 1u);   // round-to-nearest-even
    return (unsigned short)(u >> 16);
}

// ---- pre-pass: convert Wa[64x256], Wb[64x256], Wg[256x256] f32 -> bf16 in d_ws ----
__global__ void convert_weights(const float* __restrict__ Wa,
                                const float* __restrict__ Wb,
                                const float* __restrict__ Wg,
                                unsigned short* __restrict__ wsB)
{
    int base = (blockIdx.x * 256 + threadIdx.x) * 4;     // 24576 threads x 4 elems
    const float* src;
    if (base < 16384)      src = Wa + base;
    else if (base < 32768) src = Wb + (base - 16384);
    else                   src = Wg + (base - 32768);
    float4 v = *(const float4*)src;
    s4v p;
    p[0] = (short)f2bf(v.x); p[1] = (short)f2bf(v.y);
    p[2] = (short)f2bf(v.z); p[3] = (short)f2bf(v.w);
    *(s4v*)(wsB + base) = p;
}

// LDS layout (53248 B -> 3 blocks/CU):
//   [0, 32768)      X_s [64 rows (sl*32+t)][256] bf16, 512 B rows, chunk swizzle (c+r)&31
//   [32768, 40960)  theta [64 rows][64] bf16, 128 B rows, swz (c+r)&7
//                   ...overlaid after attn barrier by featsT: per-wave [2 sl][16 f][32 u]
//   [40960, 49152)  phi   [64 rows][64] bf16
//   [49152, 53248)  attn  [64 rows (sl*32+t)][32] bf16, 64 B rows, swz (c+r)&3
#define XS_OFF 0
#define TH_OFF 32768
#define PH_OFF 40960
#define AT_OFF 49152
#define FT_OFF 32768    // overlays theta (dead after attn barrier)
#define LDS_BYTES 53248

// (256,3): VGPR cap ~170, fits peak ~130-150 (wa/wb frags 64 + accs 32 + stream).
// History: (256,5) spilled afrag -> +380 MB scratch, dur 145->226. (256,4) cap 128
// is too tight for the NS=2 register set. Keep 3; check hbm_bytes ~2.03e8 for no-spill.
__global__ __launch_bounds__(256, 3) void fused_temporal(
    const float* __restrict__ X,
    const unsigned short* __restrict__ wsB,
    const float* __restrict__ ba, const float* __restrict__ bb,
    const float* __restrict__ bg,
    float* __restrict__ out)
{
    __shared__ alignas(16) unsigned char smem[LDS_BYTES];
    const int tid  = threadIdx.x;
    const int wave = tid >> 6;
    const int lane = tid & 63;
    const int quad = lane >> 4;
    const int l15  = lane & 15;
    const int s0   = blockIdx.x * NS;

    const unsigned short* WaB = wsB;
    const unsigned short* WbB = wsB + 16384;
    const unsigned short* WgB = wsB + 32768;

    // ---- Stage A: stage X for NS s-values [64 rows x 256 f32] -> bf16 LDS, swizzled ----
    #pragma unroll
    for (int i = 0; i < 8; ++i) {
        int linear = i * 256 + tid;            // 0..2047 chunks of 8 f32
        int r = linear >> 5;                   // LDS row 0..63  (sl*32 + t)
        int c = linear & 31;                   // 8-elem chunk in row
        int t  = r & 31;
        int sl = r >> 5;
        const float* xp = X + ((size_t)(t * S_ + s0 + sl)) * F_ + c * 8;
        float4 v0 = *(const float4*)(xp);
        float4 v1 = *(const float4*)(xp + 4);
        s8v p;
        p[0] = (short)f2bf(v0.x); p[1] = (short)f2bf(v0.y);
        p[2] = (short)f2bf(v0.z); p[3] = (short)f2bf(v0.w);
        p[4] = (short)f2bf(v1.x); p[5] = (short)f2bf(v1.y);
        p[6] = (short)f2bf(v1.z); p[7] = (short)f2bf(v1.w);
        *(s8v*)(&smem[XS_OFF + r * 512 + (((c + r) & 31) << 4)]) = p;
    }
    __syncthreads();

    // ---- Stage B: theta & phi over M=64 rows; wave w owns A-cols [16w,16w+16) ----
    s8v wg[2][8];   // Wg double-buffer (loaded after wa/wb die)
    {
        const int n0 = 16 * wave;
        s8v wafrag[8], wbfrag[8];
        {
            const unsigned short* wa_row = WaB + (size_t)(n0 + l15) * F_ + quad * 8;
            const unsigned short* wb_row = WbB + (size_t)(n0 + l15) * F_ + quad * 8;
            #pragma unroll
            for (int ks = 0; ks < 8; ++ks) {
                wafrag[ks] = *(const s8v*)(wa_row + ks * 32);
                wbfrag[ks] = *(const s8v*)(wb_row + ks * 32);
            }
        }

        f4v ta[4], pa[4];
        #pragma unroll
        for (int mt = 0; mt < 4; ++mt) { ta[mt] = f4v{0.f,0.f,0.f,0.f}; pa[mt] = f4v{0.f,0.f,0.f,0.f}; }

        #pragma unroll
        for (int ks = 0; ks < 8; ++ks) {
            int chunk = 4 * ks + quad;
            #pragma unroll
            for (int mt = 0; mt < 4; ++mt) {
                int r = 16 * mt + l15;
                s8v a = *(const s8v*)(&smem[XS_OFF + r * 512 + (((chunk + r) & 31) << 4)]);
                ta[mt] = MFMA(a, wafrag[ks], ta[mt]);
                pa[mt] = MFMA(a, wbfrag[ks], pa[mt]);
            }
        }

        // prefetch Wg for g=0,1 (wa/wb now dead; loads overlap epilogue + attn phase)
        #pragma unroll
        for (int g = 0; g < 2; ++g) {
            const unsigned short* wg_row = WgB + (size_t)(64 * wave + 16 * g + l15) * F_ + quad * 8;
            #pragma unroll
            for (int ks = 0; ks < 8; ++ks) wg[g][ks] = *(const s8v*)(wg_row + ks * 32);
        }

        float biasa = ba[n0 + l15];
        float biasb = bb[n0 + l15];
        int a_col = n0 + l15;
        int chunk = a_col >> 3;
        int sub   = (a_col & 7) * 2;
        #pragma unroll
        for (int mt = 0; mt < 4; ++mt) {
            #pragma unroll
            for (int r = 0; r < 4; ++r) {
                int row = 16 * mt + quad * 4 + r;       // LDS row (sl*32 + t)
                int sw  = ((chunk + row) & 7) << 4;
                *(unsigned short*)(&smem[TH_OFF + row * 128 + sw + sub]) = f2bf(ta[mt][r] + biasa);
                *(unsigned short*)(&smem[PH_OFF + row * 128 + sw + sub]) = f2bf(pa[mt][r] + biasb);
            }
        }
    }
    __syncthreads();

    // ---- Attn: per s, attn[t][u] = sum_a theta*phi. Wave w: sl=w>>1, t-tile=w&1, loop u-tiles ----
    {
        int sl  = wave >> 1;
        int mt2 = wave & 1;
        int t2  = l15 + 16 * mt2;
        int rth = sl * 32 + t2;
        #pragma unroll
        for (int nt2 = 0; nt2 < 2; ++nt2) {
            int u2  = l15 + 16 * nt2;
            int rph = sl * 32 + u2;
            f4v acc2 = {0.f,0.f,0.f,0.f};
            #pragma unroll
            for (int ks = 0; ks < 2; ++ks) {
                int chunk = 4 * ks + quad;
                s8v av = *(const s8v*)(&smem[TH_OFF + rth * 128 + (((chunk + rth) & 7) << 4)]);
                s8v bv = *(const s8v*)(&smem[PH_OFF + rph * 128 + (((chunk + rph) & 7) << 4)]);
                acc2 = MFMA(av, bv, acc2);
            }
            int chunk = u2 >> 3;
            int sub   = (u2 & 7) * 2;
            #pragma unroll
            for (int r = 0; r < 4; ++r) {
                int tt  = quad * 4 + r + 16 * mt2;
                int rat = sl * 32 + tt;
                *(unsigned short*)(&smem[AT_OFF + rat * 64 + (((chunk + rat) & 3) << 4) + sub]) = f2bf(acc2[r]);
            }
        }
    }
    __syncthreads();
    // After this barrier: theta/phi dead (featsT overlays theta); attn read-only;
    // featsT rows are wave-private -> stage C/D is barrier-free.

    // ---- Stage C/D fused per 16-col group g: feats -> featsT (LDS transpose) -> PV -> store ----
    {
        // attn B-frags: B[k=u][n=t], lane n=t=l15+16nt, k=quad*8+j
        s8v battn[2][2];
        #pragma unroll
        for (int sl = 0; sl < 2; ++sl) {
            #pragma unroll
            for (int nt = 0; nt < 2; ++nt) {
                int rat = sl * 32 + l15 + 16 * nt;
                battn[sl][nt] = *(const s8v*)(&smem[AT_OFF + rat * 64 + (((quad + rat) & 3) << 4)]);
            }
        }

        const int ftbase = FT_OFF + wave * 2048;   // per-wave [2 sl][16 f][32 u] bf16

        #pragma unroll
        for (int g = 0; g < 4; ++g) {
            int n0 = 64 * wave + 16 * g;
            f4v fa[4];
            #pragma unroll
            for (int mt = 0; mt < 4; ++mt) fa[mt] = f4v{0.f,0.f,0.f,0.f};
            #pragma unroll
            for (int ks = 0; ks < 8; ++ks) {
                int chunk = 4 * ks + quad;
                #pragma unroll
                for (int mt = 0; mt < 4; ++mt) {
                    int r = 16 * mt + l15;
                    s8v a = *(const s8v*)(&smem[XS_OFF + r * 512 + (((chunk + r) & 31) << 4)]);
                    fa[mt] = MFMA(a, wg[g & 1][ks], fa[mt]);
                }
            }
            // prefetch wg for g+2 into the buffer just freed
            if (g < 2) {
                const unsigned short* wg_row = WgB + (size_t)(64 * wave + 16 * (g + 2) + l15) * F_ + quad * 8;
                #pragma unroll
                for (int ks = 0; ks < 8; ++ks) wg[g & 1][ks] = *(const s8v*)(wg_row + ks * 32);
            }

            float biasg = bg[n0 + l15];
            // featsT write: D row = 16mt + quad*4+r -> (sl = mt>>1, u = (mt&1)*16 + quad*4 + r), col f=l15
            #pragma unroll
            for (int mt = 0; mt < 4; ++mt) {
                int sl = mt >> 1;
                int u0 = (mt & 1) * 16 + quad * 4;      // 4 consecutive u per lane
                s4v pk;
                #pragma unroll
                for (int r = 0; r < 4; ++r) pk[r] = (short)f2bf(fa[mt][r] + biasg);
                int addr = ftbase + sl * 1024 + l15 * 64 + ((((u0 >> 3) + l15) & 3) << 4) + (u0 & 7) * 2;
                *(s4v*)(&smem[addr]) = pk;              // ds_write_b64, wave-private
            }

            // PV: A-frag featsT[f=l15][u=quad*8+j]; D: col=l15->t, row=quad*4+r->f (consecutive f)
            int f0 = n0 + 4 * quad;
            #pragma unroll
            for (int sl = 0; sl < 2; ++sl) {
                s8v avf = *(const s8v*)(&smem[ftbase + sl * 1024 + l15 * 64 + (((quad + l15) & 3) << 4)]);
                #pragma unroll
                for (int nt = 0; nt < 2; ++nt) {
                    f4v z = {0.f,0.f,0.f,0.f};
                    f4v acc = MFMA(avf, battn[sl][nt], z);
                    int t = l15 + 16 * nt;
                    float4 st;
                    st.x = acc[0]; st.y = acc[1]; st.z = acc[2]; st.w = acc[3];
                    *(float4*)(out + ((size_t)(t * S_ + s0 + sl)) * F_ + f0) = st;
                }
            }
        }
    }
}

extern "C" void kernel_launch(void* const* d_in, const int* in_sizes, int n_in,
                              void* d_out, int out_size, void* d_ws, size_t ws_size,
                              hipStream_t stream) {
    (void)in_sizes; (void)n_in; (void)ws_size; (void)out_size;
    const float* X  = (const float*)d_in[0];   // batch_data [T*S, F] f32
    // d_in[1] = xywh (dead path)
    const float* Wa = (const float*)d_in[2];
    const float* ba = (const float*)d_in[3];
    const float* Wb = (const float*)d_in[4];
    const float* bb = (const float*)d_in[5];
    const float* Wg = (const float*)d_in[6];
    const float* bg = (const float*)d_in[7];
    // d_in[8] = Wh, d_in[9] = bh (dead path)
    float* out = (float*)d_out;
    unsigned short* wsB = (unsigned short*)d_ws;   // 192 KB bf16 weights

    convert_weights<<<dim3(96), dim3(256), 0, stream>>>(Wa, Wb, Wg, wsB);
    fused_temporal<<<dim3(S_ / NS), dim3(256), 0, stream>>>(X, wsB, ba, bb, bg, out);
}

// Round 5
// 305.050 us; speedup vs baseline: 1.2971x; 1.0314x over previous
//
#include <hip/hip_runtime.h>

#define T_ 32
#define S_ 4096
#define F_ 256
#define A_ 64
#define NS 2                     // s-values per iteration
#define GRID 256                 // persistent blocks, 1 per CU
#define ITERS (S_ / NS / GRID)   // 8

typedef __attribute__((ext_vector_type(8))) short s8v;   // 8 x bf16 (MFMA A/B frag)
typedef __attribute__((ext_vector_type(4))) float f4v;   // 4 x f32  (MFMA C/D frag)
typedef __attribute__((ext_vector_type(4))) short s4v;   // 8-byte packed store

#define MFMA(a, b, c) __builtin_amdgcn_mfma_f32_16x16x32_bf16((a), (b), (c), 0, 0, 0)

__device__ __forceinline__ unsigned short f2bf(float f) {
    unsigned int u = __builtin_bit_cast(unsigned int, f);
    u += 0x7FFFu + ((u >> 16) & 1u);   // round-to-nearest-even
    return (unsigned short)(u >> 16);
}

// ---- pre-pass: convert Wa[64x256], Wb[64x256], Wg[256x256] f32 -> bf16 in d_ws ----
__global__ void convert_weights(const float* __restrict__ Wa,
                                const float* __restrict__ Wb,
                                const float* __restrict__ Wg,
                                unsigned short* __restrict__ wsB)
{
    int base = (blockIdx.x * 256 + threadIdx.x) * 4;     // 24576 threads x 4 elems
    const float* src;
    if (base < 16384)      src = Wa + base;
    else if (base < 32768) src = Wb + (base - 16384);
    else                   src = Wg + (base - 32768);
    float4 v = *(const float4*)src;
    s4v p;
    p[0] = (short)f2bf(v.x); p[1] = (short)f2bf(v.y);
    p[2] = (short)f2bf(v.z); p[3] = (short)f2bf(v.w);
    *(s4v*)(wsB + base) = p;
}

// LDS layout (151552 B -> 1 block/CU, persistent):
//   [0, 32768)        X buf0 [64 rows][256] bf16, 512 B rows, chunk swz (c+r)&31
//   [32768, 65536)    X buf1 (double buffer)
//   [65536, 131072)   Wa|Wb [128 rows][256] bf16 (Wa rows 0-63, Wb 64-127), swz (c+r)&31
//   [131072, 139264)  theta [64][64] bf16, 128 B rows, swz (c+r)&7; featsT overlay in stage C
//   [139264, 147456)  phi   [64][64] bf16
//   [147456, 151552)  attn  [64][32] bf16, 64 B rows, swz (c+r)&3
#define X0_OFF 0
#define X1_OFF 32768
#define WW_OFF 65536
#define TH_OFF 131072
#define PH_OFF 139264
#define AT_OFF 147456
#define FT_OFF TH_OFF
#define LDS_BYTES 151552

// Custom barrier: lgkmcnt-only (all cross-wave deps are LDS). __syncthreads would
// emit s_waitcnt vmcnt(0) and drain the cross-iteration X prefetch. The asm memory
// clobber also pins prefetch loads against sinking. sched_barrier(0) per rule #18.
#define BAR() do {                                            \
    asm volatile("s_waitcnt lgkmcnt(0)" ::: "memory");        \
    __builtin_amdgcn_s_barrier();                             \
    __builtin_amdgcn_sched_barrier(0);                        \
} while (0)

// (256,1): VGPR cap 512. We WANT ~300 VGPRs (wg[4][8]=128 resident + fa[4][4]=64 +
// xnext=64). History: caps of 102/128 forced the compiler to sink/spill weight
// fragments every round (VGPR_Count 48-84, weights re-fetched from L2 at use).
__global__ __launch_bounds__(256, 1) void fused_temporal(
    const float* __restrict__ X,
    const unsigned short* __restrict__ wsB,
    const float* __restrict__ ba, const float* __restrict__ bb,
    const float* __restrict__ bg,
    float* __restrict__ out)
{
    __shared__ alignas(16) unsigned char smem[LDS_BYTES];
    const int tid  = threadIdx.x;
    const int wave = tid >> 6;
    const int lane = tid & 63;
    const int quad = lane >> 4;
    const int l15  = lane & 15;
    const int b    = blockIdx.x;

    const unsigned short* WgB = wsB + 32768;

    // ================= PROLOGUE (once per block) =================
    // 1) Wa|Wb -> LDS, swizzled. wsB shorts [0,32768) are Wa rows 0-63, Wb rows 64-127.
    #pragma unroll
    for (int i = 0; i < 16; ++i) {
        int cid = i * 256 + tid;               // 0..4095 chunks of 8 shorts
        int r = cid >> 5, c = cid & 31;
        s8v v = *(const s8v*)(wsB + (size_t)cid * 8);
        *(s8v*)(&smem[WW_OFF + r * 512 + (((c + r) & 31) << 4)]) = v;
    }
    // 2) Wg -> registers, once. wave w owns cols [64w, 64w+64): wg[g][ks], 128 VGPRs.
    s8v wg[4][8];
    #pragma unroll
    for (int g = 0; g < 4; ++g) {
        const unsigned short* p = WgB + (size_t)(64 * wave + 16 * g + l15) * F_ + quad * 8;
        #pragma unroll
        for (int ks = 0; ks < 8; ++ks) wg[g][ks] = *(const s8v*)(p + ks * 32);
    }
    // 3) X for it=0 -> buf0 (direct convert)
    {
        int s0 = b * NS;
        #pragma unroll
        for (int i = 0; i < 8; ++i) {
            int linear = i * 256 + tid;
            int r = linear >> 5, c = linear & 31;
            int t = r & 31, sl = r >> 5;
            const float* xp = X + ((size_t)(t * S_ + s0 + sl)) * F_ + c * 8;
            float4 v0 = *(const float4*)(xp);
            float4 v1 = *(const float4*)(xp + 4);
            s8v p;
            p[0] = (short)f2bf(v0.x); p[1] = (short)f2bf(v0.y);
            p[2] = (short)f2bf(v0.z); p[3] = (short)f2bf(v0.w);
            p[4] = (short)f2bf(v1.x); p[5] = (short)f2bf(v1.y);
            p[6] = (short)f2bf(v1.z); p[7] = (short)f2bf(v1.w);
            *(s8v*)(&smem[X0_OFF + r * 512 + (((c + r) & 31) << 4)]) = p;
        }
    }
    float biasa = ba[16 * wave + l15];
    float biasb = bb[16 * wave + l15];
    BAR();

    // ================= PERSISTENT LOOP over s-pairs =================
    float4 xnx[16];
    #pragma unroll 1
    for (int it = 0; it < ITERS; ++it) {
        const int xs = (it & 1) ? X1_OFF : X0_OFF;
        const int xd = (it & 1) ? X0_OFF : X1_OFF;
        const int s0 = (it * GRID + b) * NS;

        // ---- issue next-iteration X loads (in flight across the whole iteration) ----
        if (it + 1 < ITERS) {
            int sn = ((it + 1) * GRID + b) * NS;
            #pragma unroll
            for (int i = 0; i < 8; ++i) {
                int linear = i * 256 + tid;
                int r = linear >> 5, c = linear & 31;
                int t = r & 31, sl = r >> 5;
                const float* xp = X + ((size_t)(t * S_ + sn + sl)) * F_ + c * 8;
                xnx[2 * i]     = *(const float4*)(xp);
                xnx[2 * i + 1] = *(const float4*)(xp + 4);
            }
        }

        // ---- Stage B: theta & phi (A from X-LDS, W from Wa/Wb-LDS) ----
        {
            const int n0 = 16 * wave;
            const int ra = n0 + l15;            // Wa LDS row
            const int rb = 64 + n0 + l15;       // Wb LDS row
            f4v ta[4], pa[4];
            #pragma unroll
            for (int mt = 0; mt < 4; ++mt) { ta[mt] = f4v{0.f,0.f,0.f,0.f}; pa[mt] = f4v{0.f,0.f,0.f,0.f}; }
            #pragma unroll
            for (int ks = 0; ks < 8; ++ks) {
                int chunk = 4 * ks + quad;
                s8v bfa = *(const s8v*)(&smem[WW_OFF + ra * 512 + (((chunk + ra) & 31) << 4)]);
                s8v bfb = *(const s8v*)(&smem[WW_OFF + rb * 512 + (((chunk + rb) & 31) << 4)]);
                #pragma unroll
                for (int mt = 0; mt < 4; ++mt) {
                    int r = 16 * mt + l15;
                    s8v a = *(const s8v*)(&smem[xs + r * 512 + (((chunk + r) & 31) << 4)]);
                    ta[mt] = MFMA(a, bfa, ta[mt]);
                    pa[mt] = MFMA(a, bfb, pa[mt]);
                }
            }
            int a_col = n0 + l15;
            int chunk = a_col >> 3;
            int sub   = (a_col & 7) * 2;
            #pragma unroll
            for (int mt = 0; mt < 4; ++mt) {
                #pragma unroll
                for (int r = 0; r < 4; ++r) {
                    int row = 16 * mt + quad * 4 + r;
                    int sw  = ((chunk + row) & 7) << 4;
                    *(unsigned short*)(&smem[TH_OFF + row * 128 + sw + sub]) = f2bf(ta[mt][r] + biasa);
                    *(unsigned short*)(&smem[PH_OFF + row * 128 + sw + sub]) = f2bf(pa[mt][r] + biasb);
                }
            }
        }
        BAR();

        // ---- Attn: per sl, attn[t][u]; wave w: sl=w>>1, t-tile=w&1 ----
        {
            int sl  = wave >> 1;
            int mt2 = wave & 1;
            int t2  = l15 + 16 * mt2;
            int rth = sl * 32 + t2;
            #pragma unroll
            for (int nt2 = 0; nt2 < 2; ++nt2) {
                int u2  = l15 + 16 * nt2;
                int rph = sl * 32 + u2;
                f4v acc2 = {0.f,0.f,0.f,0.f};
                #pragma unroll
                for (int ks = 0; ks < 2; ++ks) {
                    int chunk = 4 * ks + quad;
                    s8v av = *(const s8v*)(&smem[TH_OFF + rth * 128 + (((chunk + rth) & 7) << 4)]);
                    s8v bv = *(const s8v*)(&smem[PH_OFF + rph * 128 + (((chunk + rph) & 7) << 4)]);
                    acc2 = MFMA(av, bv, acc2);
                }
                int chunk = u2 >> 3;
                int sub   = (u2 & 7) * 2;
                #pragma unroll
                for (int r = 0; r < 4; ++r) {
                    int tt  = quad * 4 + r + 16 * mt2;
                    int rat = sl * 32 + tt;
                    *(unsigned short*)(&smem[AT_OFF + rat * 64 + (((chunk + rat) & 3) << 4) + sub]) = f2bf(acc2[r]);
                }
            }
        }
        BAR();
        // theta/phi dead; featsT (wave-private) overlays theta; attn read-only.

        // ---- Stage C/D: feats (wg regs) -> featsT -> PV -> out ----
        {
            s8v battn[2][2];
            #pragma unroll
            for (int sl = 0; sl < 2; ++sl) {
                #pragma unroll
                for (int nt = 0; nt < 2; ++nt) {
                    int rat = sl * 32 + l15 + 16 * nt;
                    battn[sl][nt] = *(const s8v*)(&smem[AT_OFF + rat * 64 + (((quad + rat) & 3) << 4)]);
                }
            }
            const int ftbase = FT_OFF + wave * 2048;   // per-wave [2 sl][16 f][32 u]

            // ks-outer: one A-read feeds all 4 g-groups (X re-reads cut 4x)
            f4v fa[4][4];
            #pragma unroll
            for (int g = 0; g < 4; ++g)
                #pragma unroll
                for (int mt = 0; mt < 4; ++mt) fa[g][mt] = f4v{0.f,0.f,0.f,0.f};
            #pragma unroll
            for (int ks = 0; ks < 8; ++ks) {
                int chunk = 4 * ks + quad;
                s8v a[4];
                #pragma unroll
                for (int mt = 0; mt < 4; ++mt) {
                    int r = 16 * mt + l15;
                    a[mt] = *(const s8v*)(&smem[xs + r * 512 + (((chunk + r) & 31) << 4)]);
                }
                #pragma unroll
                for (int g = 0; g < 4; ++g)
                    #pragma unroll
                    for (int mt = 0; mt < 4; ++mt)
                        fa[g][mt] = MFMA(a[mt], wg[g][ks], fa[g][mt]);
            }

            #pragma unroll
            for (int g = 0; g < 4; ++g) {
                int n0 = 64 * wave + 16 * g;
                float biasg = bg[n0 + l15];
                #pragma unroll
                for (int mt = 0; mt < 4; ++mt) {
                    int sl = mt >> 1;
                    int u0 = (mt & 1) * 16 + quad * 4;
                    s4v pk;
                    #pragma unroll
                    for (int r = 0; r < 4; ++r) pk[r] = (short)f2bf(fa[g][mt][r] + biasg);
                    int addr = ftbase + sl * 1024 + l15 * 64 + ((((u0 >> 3) + l15) & 3) << 4) + (u0 & 7) * 2;
                    *(s4v*)(&smem[addr]) = pk;
                }
                int f0 = n0 + 4 * quad;
                #pragma unroll
                for (int sl = 0; sl < 2; ++sl) {
                    s8v avf = *(const s8v*)(&smem[ftbase + sl * 1024 + l15 * 64 + (((quad + l15) & 3) << 4)]);
                    #pragma unroll
                    for (int nt = 0; nt < 2; ++nt) {
                        f4v z = {0.f,0.f,0.f,0.f};
                        f4v acc = MFMA(avf, battn[sl][nt], z);
                        int t = l15 + 16 * nt;
                        float4 st;
                        st.x = acc[0]; st.y = acc[1]; st.z = acc[2]; st.w = acc[3];
                        *(float4*)(out + ((size_t)(t * S_ + s0 + sl)) * F_ + f0) = st;
                    }
                }
            }
        }

        // ---- convert prefetched X into the other buffer ----
        if (it + 1 < ITERS) {
            #pragma unroll
            for (int i = 0; i < 8; ++i) {
                int linear = i * 256 + tid;
                int r = linear >> 5, c = linear & 31;
                float4 v0 = xnx[2 * i];
                float4 v1 = xnx[2 * i + 1];
                s8v p;
                p[0] = (short)f2bf(v0.x); p[1] = (short)f2bf(v0.y);
                p[2] = (short)f2bf(v0.z); p[3] = (short)f2bf(v0.w);
                p[4] = (short)f2bf(v1.x); p[5] = (short)f2bf(v1.y);
                p[6] = (short)f2bf(v1.z); p[7] = (short)f2bf(v1.w);
                *(s8v*)(&smem[xd + r * 512 + (((c + r) & 31) << 4)]) = p;
            }
        }
        BAR();   // X[xd] visible; featsT<->theta handoff for next iteration
    }
}

extern "C" void kernel_launch(void* const* d_in, const int* in_sizes, int n_in,
                              void* d_out, int out_size, void* d_ws, size_t ws_size,
                              hipStream_t stream) {
    (void)in_sizes; (void)n_in; (void)ws_size; (void)out_size;
    const float* X  = (const float*)d_in[0];   // batch_data [T*S, F] f32
    // d_in[1] = xywh (dead path)
    const float* Wa = (const float*)d_in[2];
    const float* ba = (const float*)d_in[3];
    const float* Wb = (const float*)d_in[4];
    const float* bb = (const float*)d_in[5];
    const float* Wg = (const float*)d_in[6];
    const float* bg = (const float*)d_in[7];
    // d_in[8] = Wh, d_in[9] = bh (dead path)
    float* out = (float*)d_out;
    unsigned short* wsB = (unsigned short*)d_ws;   // 192 KB bf16 weights

    convert_weights<<<dim3(96), dim3(256), 0, stream>>>(Wa, Wb, Wg, wsB);
    fused_temporal<<<dim3(GRID), dim3(256), 0, stream>>>(X, wsB, ba, bb, bg, out);
}